// Round 1
// baseline (992.280 us; speedup 1.0000x reference)
//
#include <hip/hip_runtime.h>
#include <hip/hip_bf16.h>
#include <stdint.h>

// Problem constants (compile-time; shapes fixed by setup_inputs()).
#define M_ROWS 4096      // batch rows of x
#define IN_F   4096      // K
#define OUT_F  11008     // N
#define N_GROUPS 32      // IN_F / 128
#define ALPHA  0.05f

typedef __bf16 bf16;
typedef __bf16 bf16x8 __attribute__((ext_vector_type(8)));
typedef float  floatx4 __attribute__((ext_vector_type(4)));

// async global->LDS, 16B per lane; LDS dest = wave-uniform base + lane*16
__device__ __forceinline__ void async_copy16(const void* g, void* l) {
  __builtin_amdgcn_global_load_lds(
      (const __attribute__((address_space(1))) void*)g,
      (__attribute__((address_space(3))) void*)l, 16, 0, 0);
}

// ---------------------------------------------------------------------------
// Phase 1a: w_noisy[o,i] = (q - zeros[o,g])*scales[o,g] * (1 + ...) -> bf16
// 8 elems/thread: 2x int4 (q) + 2x float4 (noise) -> 1x 16B bf16 store.
// ---------------------------------------------------------------------------
__global__ __launch_bounds__(256) void dequant_noise_kernel(
    const int* __restrict__ q, const float* __restrict__ scales,
    const float* __restrict__ zeros, const float* __restrict__ noise,
    bf16* __restrict__ wn) {
  int gid = blockIdx.x * 256 + threadIdx.x;   // 512 threads per output row
  int o = gid >> 9;
  int i = (gid & 511) << 3;                   // 8-aligned -> single group
  int g = i >> 7;
  float s = scales[o * N_GROUPS + g];
  float z = zeros[o * N_GROUPS + g];
  size_t base = (size_t)o * IN_F + i;
  int4   q0 = *(const int4*)(q + base);
  int4   q1 = *(const int4*)(q + base + 4);
  float4 n0 = *(const float4*)(noise + base);
  float4 n1 = *(const float4*)(noise + base + 4);
  float qs[8] = {(float)q0.x, (float)q0.y, (float)q0.z, (float)q0.w,
                 (float)q1.x, (float)q1.y, (float)q1.z, (float)q1.w};
  float ns[8] = {n0.x, n0.y, n0.z, n0.w, n1.x, n1.y, n1.z, n1.w};
  bf16x8 out;
#pragma unroll
  for (int j = 0; j < 8; ++j) {
    float w = (qs[j] - z) * s;
    float v = fmaf(ALPHA * fabsf(w), ns[j], w);   // w + noise*ALPHA*|w|
    out[j] = (bf16)v;
  }
  *(bf16x8*)(wn + base) = out;
}

// ---------------------------------------------------------------------------
// Phase 1b: x fp32 -> bf16
// ---------------------------------------------------------------------------
__global__ __launch_bounds__(256) void xcast_kernel(
    const float* __restrict__ x, bf16* __restrict__ xb) {
  size_t base = ((size_t)blockIdx.x * 256 + threadIdx.x) << 3;
  float4 a0 = *(const float4*)(x + base);
  float4 a1 = *(const float4*)(x + base + 4);
  float vs[8] = {a0.x, a0.y, a0.z, a0.w, a1.x, a1.y, a1.z, a1.w};
  bf16x8 out;
#pragma unroll
  for (int j = 0; j < 8; ++j) out[j] = (bf16)vs[j];
  *(bf16x8*)(xb + base) = out;
}

// ---------------------------------------------------------------------------
// Phase 2: C[m][n] = sum_k A[m][k]*W[n][k] + bias[n]   (A=x bf16, W=wn bf16)
// m97 structure: 128x128 tile, BK=64, 256 thr = 4 waves, each wave a 64x64
// quadrant = 4x4 of 16x16x32 bf16 MFMA. global_load_lds width=16, LDS tiles
// [128][64] unpadded (required by the wave-uniform-base lane mapping).
// ---------------------------------------------------------------------------
__global__ __launch_bounds__(256) void gemm_bt_kernel(
    const bf16* __restrict__ A,    // [M_ROWS][IN_F]
    const bf16* __restrict__ W,    // [OUT_F][IN_F]
    const float* __restrict__ bias,
    float* __restrict__ C) {       // [M_ROWS][OUT_F]
  __shared__ bf16 ldsA[128 * 64];
  __shared__ bf16 ldsB[128 * 64];
  const int tid = threadIdx.x;
  const int wv = tid >> 6;          // wave 0..3
  const int ln = tid & 63;
  const int wr = wv >> 1;           // wave quadrant row (0..1)
  const int wc = wv & 1;            // wave quadrant col (0..1)
  const int mbase = blockIdx.y * 128;
  const int nbase = blockIdx.x * 128;

  const int srow = ln >> 3;         // staging: row-in-8 (0..7)
  const int scol = (ln & 7) * 8;    // staging: col element offset (0..56)
  const int frow = ln & 15;         // fragment: m (A) / n (B) index
  const int fcol = (ln >> 4) * 8;   // fragment: k offset of this lane's 8 elems

  floatx4 acc[4][4] = {};           // 16 tiles x 4 fp32 = 64 acc regs

  for (int k0 = 0; k0 < IN_F; k0 += 64) {
#pragma unroll
    for (int t = 0; t < 4; ++t) {
      int rr = (wv * 4 + t) * 8 + srow;     // tile row 0..127
      async_copy16(A + (size_t)(mbase + rr) * IN_F + k0 + scol,
                   &ldsA[(wv * 4 + t) * 512]);
      async_copy16(W + (size_t)(nbase + rr) * IN_F + k0 + scol,
                   &ldsB[(wv * 4 + t) * 512]);
    }
    __syncthreads();   // compiler emits s_waitcnt vmcnt(0) before s_barrier

#pragma unroll
    for (int kk = 0; kk < 64; kk += 32) {
      bf16x8 af[4], bfr[4];
#pragma unroll
      for (int mi = 0; mi < 4; ++mi)
        af[mi] = *(const bf16x8*)&ldsA[(wr * 64 + mi * 16 + frow) * 64 + kk + fcol];
#pragma unroll
      for (int ni = 0; ni < 4; ++ni)
        bfr[ni] = *(const bf16x8*)&ldsB[(wc * 64 + ni * 16 + frow) * 64 + kk + fcol];
#pragma unroll
      for (int mi = 0; mi < 4; ++mi)
#pragma unroll
        for (int ni = 0; ni < 4; ++ni)
          acc[mi][ni] = __builtin_amdgcn_mfma_f32_16x16x32_bf16(
              af[mi], bfr[ni], acc[mi][ni], 0, 0, 0);
    }
    __syncthreads();
  }

  // Epilogue. C/D layout (m89-verified): col = lane&15, row = (lane>>4)*4 + reg.
#pragma unroll
  for (int ni = 0; ni < 4; ++ni) {
    int n = nbase + wc * 64 + ni * 16 + (ln & 15);
    float bv = bias[n];
#pragma unroll
    for (int mi = 0; mi < 4; ++mi) {
      int m0 = mbase + wr * 64 + mi * 16 + (ln >> 4) * 4;
#pragma unroll
      for (int r = 0; r < 4; ++r)
        C[(size_t)(m0 + r) * OUT_F + n] = acc[mi][ni][r] + bv;
    }
  }
}

// ---------------------------------------------------------------------------
extern "C" void kernel_launch(void* const* d_in, const int* in_sizes, int n_in,
                              void* d_out, int out_size, void* d_ws, size_t ws_size,
                              hipStream_t stream) {
  const float* x       = (const float*)d_in[0];  // [4096][4096]
  const int*   qweight = (const int*)d_in[1];    // [11008][4096]
  const float* scales  = (const float*)d_in[2];  // [11008][32]
  const float* zeros   = (const float*)d_in[3];  // [11008][32]
  const float* bias    = (const float*)d_in[4];  // [11008]
  const float* noise   = (const float*)d_in[5];  // [11008][4096]
  float* out = (float*)d_out;                    // [4096][11008]

  // Workspace layout: wn bf16 [OUT_F][IN_F] (90.2 MB), then xb bf16 (33.6 MB).
  bf16* wn = (bf16*)d_ws;
  bf16* xb = (bf16*)((char*)d_ws + (size_t)OUT_F * IN_F * sizeof(bf16));

  // Phase 1: materialize noisy weights + bf16 x (fully rewritten every call).
  dequant_noise_kernel<<<(OUT_F * (IN_F / 8)) / 256, 256, 0, stream>>>(
      qweight, scales, zeros, noise, wn);
  xcast_kernel<<<(M_ROWS * (IN_F / 8)) / 256, 256, 0, stream>>>(x, xb);

  // Phase 2: bf16 MFMA GEMM, exact tiles (4096=32*128, 11008=86*128).
  dim3 grid(OUT_F / 128, M_ROWS / 128);
  gemm_bt_kernel<<<grid, 256, 0, stream>>>(xb, wn, bias, out);
}

// Round 2
// 947.670 us; speedup vs baseline: 1.0471x; 1.0471x over previous
//
#include <hip/hip_runtime.h>
#include <hip/hip_bf16.h>
#include <stdint.h>

// Problem constants (compile-time; shapes fixed by setup_inputs()).
#define M_ROWS 4096      // batch rows of x
#define IN_F   4096      // K
#define OUT_F  11008     // N
#define N_GROUPS 32      // IN_F / 128
#define ALPHA  0.05f

typedef __bf16 bf16;
typedef __bf16 bf16x8 __attribute__((ext_vector_type(8)));
typedef float  floatx4 __attribute__((ext_vector_type(4)));

// async global->LDS, 16B per lane; LDS dest = wave-uniform base + lane*16
__device__ __forceinline__ void async_copy16(const void* g, void* l) {
  __builtin_amdgcn_global_load_lds(
      (const __attribute__((address_space(1))) void*)g,
      (__attribute__((address_space(3))) void*)l, 16, 0, 0);
}

// ---------------------------------------------------------------------------
// Phase 1a: w_noisy[o,i] = (q - zeros[o,g])*scales[o,g] + noise*ALPHA*|w| -> bf16
// ---------------------------------------------------------------------------
__global__ __launch_bounds__(256) void dequant_noise_kernel(
    const int* __restrict__ q, const float* __restrict__ scales,
    const float* __restrict__ zeros, const float* __restrict__ noise,
    bf16* __restrict__ wn) {
  int gid = blockIdx.x * 256 + threadIdx.x;   // 512 threads per output row
  int o = gid >> 9;
  int i = (gid & 511) << 3;                   // 8-aligned -> single group
  int g = i >> 7;
  float s = scales[o * N_GROUPS + g];
  float z = zeros[o * N_GROUPS + g];
  size_t base = (size_t)o * IN_F + i;
  int4   q0 = *(const int4*)(q + base);
  int4   q1 = *(const int4*)(q + base + 4);
  float4 n0 = *(const float4*)(noise + base);
  float4 n1 = *(const float4*)(noise + base + 4);
  float qs[8] = {(float)q0.x, (float)q0.y, (float)q0.z, (float)q0.w,
                 (float)q1.x, (float)q1.y, (float)q1.z, (float)q1.w};
  float ns[8] = {n0.x, n0.y, n0.z, n0.w, n1.x, n1.y, n1.z, n1.w};
  bf16x8 out;
#pragma unroll
  for (int j = 0; j < 8; ++j) {
    float w = (qs[j] - z) * s;
    float v = fmaf(ALPHA * fabsf(w), ns[j], w);   // w + noise*ALPHA*|w|
    out[j] = (bf16)v;
  }
  *(bf16x8*)(wn + base) = out;
}

// ---------------------------------------------------------------------------
// Phase 1b: x fp32 -> bf16
// ---------------------------------------------------------------------------
__global__ __launch_bounds__(256) void xcast_kernel(
    const float* __restrict__ x, bf16* __restrict__ xb) {
  size_t base = ((size_t)blockIdx.x * 256 + threadIdx.x) << 3;
  float4 a0 = *(const float4*)(x + base);
  float4 a1 = *(const float4*)(x + base + 4);
  float vs[8] = {a0.x, a0.y, a0.z, a0.w, a1.x, a1.y, a1.z, a1.w};
  bf16x8 out;
#pragma unroll
  for (int j = 0; j < 8; ++j) out[j] = (bf16)vs[j];
  *(bf16x8*)(xb + base) = out;
}

// ---------------------------------------------------------------------------
// Phase 2: C[m][n] = sum_k A[m][k]*W[n][k] + bias[n]   (A=x bf16, W=wn bf16)
// m97 structure: 128x128 tile, BK=64, 256 thr = 4 waves, each wave a 64x64
// quadrant = 4x4 of 16x16x32 bf16 MFMA, global_load_lds width=16.
//
// LDS layout: XOR-swizzled. Logical (row r, 16B-chunk c) lives at physical
// slot (r, c ^ (r&7)). Rows are 128 B = exactly 32 banks, so the un-swizzled
// fragment read (8 consecutive lanes reading one chunk column across 8 rows)
// was an 8-way bank conflict; the swizzle makes each 8-lane phase hit all 8
// bank-groups exactly once. Staging realizes the swizzle for free by
// permuting each lane's GLOBAL source chunk: lane ln fetches global chunk
// (ln&7)^(ln>>3) — still a contiguous 128 B row read per 8 lanes.
// ---------------------------------------------------------------------------
__global__ __launch_bounds__(256) void gemm_bt_kernel(
    const bf16* __restrict__ A,    // [M_ROWS][IN_F]
    const bf16* __restrict__ W,    // [OUT_F][IN_F]
    const float* __restrict__ bias,
    float* __restrict__ C) {       // [M_ROWS][OUT_F]
  __shared__ bf16 ldsA[128 * 64];
  __shared__ bf16 ldsB[128 * 64];
  const int tid = threadIdx.x;
  const int wv = tid >> 6;          // wave 0..3
  const int ln = tid & 63;
  const int wr = wv >> 1;           // wave quadrant row (0..1)
  const int wc = wv & 1;            // wave quadrant col (0..1)
  const int mbase = blockIdx.y * 128;
  const int nbase = blockIdx.x * 128;

  const int srow = ln >> 3;                 // staging: row-in-8 (0..7)
  const int scol = ((ln & 7) ^ srow) * 8;   // staging: XOR-swizzled src chunk
  const int frow = ln & 15;                 // fragment: m (A) / n (B) index
  const int g4   = ln >> 4;                 // fragment: k-chunk group (0..3)
  const int x7   = ln & 7;                  // = frow & 7, the row-XOR key

  floatx4 acc[4][4] = {};           // 16 tiles x 4 fp32 = 64 acc regs

  for (int k0 = 0; k0 < IN_F; k0 += 64) {
#pragma unroll
    for (int t = 0; t < 4; ++t) {
      int rr = (wv * 4 + t) * 8 + srow;     // tile row 0..127
      async_copy16(A + (size_t)(mbase + rr) * IN_F + k0 + scol,
                   &ldsA[(wv * 4 + t) * 512]);
      async_copy16(W + (size_t)(nbase + rr) * IN_F + k0 + scol,
                   &ldsB[(wv * 4 + t) * 512]);
    }
    __syncthreads();   // compiler emits s_waitcnt vmcnt(0) before s_barrier

#pragma unroll
    for (int kk = 0; kk < 64; kk += 32) {
      const int cb = kk >> 3;                     // logical chunk base (0 or 4)
      const int pc = (((cb + g4) ^ x7) << 3);     // physical chunk offset, elems
      bf16x8 af[4], bfr[4];
#pragma unroll
      for (int mi = 0; mi < 4; ++mi)
        af[mi] = *(const bf16x8*)&ldsA[(wr * 64 + mi * 16 + frow) * 64 + pc];
#pragma unroll
      for (int ni = 0; ni < 4; ++ni)
        bfr[ni] = *(const bf16x8*)&ldsB[(wc * 64 + ni * 16 + frow) * 64 + pc];
#pragma unroll
      for (int mi = 0; mi < 4; ++mi)
#pragma unroll
        for (int ni = 0; ni < 4; ++ni)
          acc[mi][ni] = __builtin_amdgcn_mfma_f32_16x16x32_bf16(
              af[mi], bfr[ni], acc[mi][ni], 0, 0, 0);
    }
    __syncthreads();
  }

  // Epilogue. C/D layout (m89-verified): col = lane&15, row = (lane>>4)*4 + reg.
#pragma unroll
  for (int ni = 0; ni < 4; ++ni) {
    int n = nbase + wc * 64 + ni * 16 + (ln & 15);
    float bv = bias[n];
#pragma unroll
    for (int mi = 0; mi < 4; ++mi) {
      int m0 = mbase + wr * 64 + mi * 16 + (ln >> 4) * 4;
#pragma unroll
      for (int r = 0; r < 4; ++r)
        C[(size_t)(m0 + r) * OUT_F + n] = acc[mi][ni][r] + bv;
    }
  }
}

// ---------------------------------------------------------------------------
extern "C" void kernel_launch(void* const* d_in, const int* in_sizes, int n_in,
                              void* d_out, int out_size, void* d_ws, size_t ws_size,
                              hipStream_t stream) {
  const float* x       = (const float*)d_in[0];  // [4096][4096]
  const int*   qweight = (const int*)d_in[1];    // [11008][4096]
  const float* scales  = (const float*)d_in[2];  // [11008][32]
  const float* zeros   = (const float*)d_in[3];  // [11008][32]
  const float* bias    = (const float*)d_in[4];  // [11008]
  const float* noise   = (const float*)d_in[5];  // [11008][4096]
  float* out = (float*)d_out;                    // [4096][11008]

  // Workspace layout: wn bf16 [OUT_F][IN_F] (90.2 MB), then xb bf16 (33.6 MB).
  bf16* wn = (bf16*)d_ws;
  bf16* xb = (bf16*)((char*)d_ws + (size_t)OUT_F * IN_F * sizeof(bf16));

  // Phase 1: materialize noisy weights + bf16 x (fully rewritten every call).
  dequant_noise_kernel<<<(OUT_F * (IN_F / 8)) / 256, 256, 0, stream>>>(
      qweight, scales, zeros, noise, wn);
  xcast_kernel<<<(M_ROWS * (IN_F / 8)) / 256, 256, 0, stream>>>(x, xb);

  // Phase 2: bf16 MFMA GEMM, exact tiles (4096=32*128, 11008=86*128).
  dim3 grid(OUT_F / 128, M_ROWS / 128);
  gemm_bt_kernel<<<grid, 256, 0, stream>>>(xb, wn, bias, out);
}